// Round 5
// baseline (622.969 us; speedup 1.0000x reference)
//
#include <hip/hip_runtime.h>

constexpr int NB = 256;   // batch
constexpr int NS = 64;    // seq len
constexpr int NN = 64;    // tree nodes
constexpr int NE = 300;   // embedding dim
constexpr int NH = 600;   // hidden dim
constexpr int NBLK = 512; // grid (co-resident: 3 blocks/CU by LDS * 256 CU = 768 >= 512)

typedef __attribute__((ext_vector_type(8))) short bf16x8;
typedef __attribute__((ext_vector_type(4))) float f32x4;

// FC GEMM geometry: K padded to 32, N padded to 640 (40 j-tiles of 16)
constexpr int KT0 = 57;   // ceil(1800/32)  -> K=1824 for layer 0
constexpr int KT1 = 19;   // ceil(600/32)   -> K=608 for layers 1/2
constexpr int NJT = 40;   // 640 / 16 j-tiles
constexpr int HP  = 640;  // h row stride in ushorts (cols 600..607 zeroed)

// ---------------- workspace layout (float-indexed) ----------------
constexpr size_t OFF_REP = 0;                           // [2][NB][NE] fp32
constexpr size_t SZ_REP  = (size_t)2*NB*NE;
constexpr size_t OFF_ROOT= OFF_REP + SZ_REP;            // [2][NB][NE] fp32
constexpr size_t OFF_WBF = OFF_ROOT + SZ_REP;           // tree W_enc bf16 B-frag swizzled
constexpr size_t SZ_WBF  = (size_t)3*20*10*64*8/2;      // 153,600 floats
constexpr size_t OFF_W0S = OFF_WBF + SZ_WBF;            // W0 bf16 B-frag swizzled
constexpr size_t SZ_W0S  = (size_t)KT0*NJT*64*8/2;
constexpr size_t OFF_W1S = OFF_W0S + SZ_W0S;
constexpr size_t SZ_W1S  = (size_t)KT1*NJT*64*8/2;
constexpr size_t OFF_W2S = OFF_W1S + SZ_W1S;
constexpr size_t OFF_XSW = OFF_W2S + SZ_W1S;            // X bf16 A-frag swizzled
constexpr size_t SZ_XSW  = (size_t)KT0*16*64*8/2;
constexpr size_t OFF_H1  = OFF_XSW + SZ_XSW;            // h bf16 [NB][HP]
constexpr size_t SZ_H    = (size_t)NB*HP/2;
constexpr size_t OFF_H2  = OFF_H1 + SZ_H;
constexpr size_t OFF_H3  = OFF_H2 + SZ_H;
constexpr size_t OFF_CNT = OFF_H3 + SZ_H;               // barrier counter (1 u32)

__device__ __forceinline__ ushort f2bf(float x) {
  unsigned u = __float_as_uint(x);
  unsigned r = (u + 0x7FFFu + ((u >> 16) & 1u)) >> 16;   // RNE
  return (ushort)r;
}
__device__ __forceinline__ float bf2f(ushort u) {
  return __uint_as_float(((unsigned)u) << 16);
}

// Software grid barrier. Monotonic counter (memset to 0 each launch).
// Arrive: atomicAdd (device-scope RMW, pipelined). Poll: relaxed atomic LOAD
// (agent scope) — a coherent read, NOT an RMW, so pollers don't serialize the
// arrival RMWs (R4 lesson: RMW-poll cost ~55us/barrier).
__device__ __forceinline__ void gridbar(unsigned* cnt, unsigned target) {
  __syncthreads();
  if (threadIdx.x == 0) {
    __threadfence();   // release this block's writes
    atomicAdd(cnt, 1u);
    while (__hip_atomic_load(cnt, __ATOMIC_RELAXED, __HIP_MEMORY_SCOPE_AGENT) < target)
      __builtin_amdgcn_s_sleep(2);
    __threadfence();   // acquire before reading other blocks' writes
  }
  __syncthreads();
}

// setup-stage item counts
constexpr int NSWZ = 3*20*10*64;          // 38400 tree lane-frags
constexpr int N0S  = KT0*NJT*64;          // 145,920
constexpr int N1S  = KT1*NJT*64;          // 48,640
constexpr int SETUP_ITEMS = NSWZ + N0S + 2*N1S;   // 281,600
constexpr int FEAT_ITEMS  = KT0*16*64;            // 58,368

constexpr int TS = 328;   // tree LDS row stride (ushorts)

// ---- FC layer: 160 active blocks, tile = 16 rows x 64 cols, 4-way K-split ----
// Xs != nullptr: A-frag swizzled input (layer 0). Else row-major bf16 [NB][HP].
__device__ void fc_layer(const ushort* __restrict__ Arm,
                         const ushort* __restrict__ Xs,
                         const ushort* __restrict__ Wsw,
                         const float* __restrict__ bias,
                         ushort* __restrict__ hout,
                         int nkt, float* red) {
  const int blk = blockIdx.x;
  if (blk >= 160) return;
  const int tid = threadIdx.x, wv = tid >> 6, lane = tid & 63;
  const int bx = blk / 10, by = blk % 10;       // bx: 16-row tile, by: 64-col tile

  const ushort* ap;
  size_t ast;
  if (Xs) {
    ap  = Xs + (((size_t)wv*16 + bx)*64 + lane)*8;
    ast = (size_t)4*16*64*8;
  } else {
    ap  = Arm + ((size_t)(bx*16 + (lane & 15)))*HP + ((lane >> 4)*8) + (size_t)wv*32;
    ast = (size_t)4*32;
  }
  const ushort* wp = Wsw + (((size_t)wv*NJT + (size_t)by*4)*64 + lane)*8;
  const size_t wst = (size_t)4*NJT*64*8;

  f32x4 acc0{0.f,0.f,0.f,0.f}, acc1{0.f,0.f,0.f,0.f};
  f32x4 acc2{0.f,0.f,0.f,0.f}, acc3{0.f,0.f,0.f,0.f};
  for (int t = wv; t < nkt; t += 4) {
    bf16x8 a  = *reinterpret_cast<const bf16x8*>(ap);
    bf16x8 w0 = *reinterpret_cast<const bf16x8*>(wp);
    bf16x8 w1 = *reinterpret_cast<const bf16x8*>(wp + 512);
    bf16x8 w2 = *reinterpret_cast<const bf16x8*>(wp + 1024);
    bf16x8 w3 = *reinterpret_cast<const bf16x8*>(wp + 1536);
    acc0 = __builtin_amdgcn_mfma_f32_16x16x32_bf16(a, w0, acc0, 0, 0, 0);
    acc1 = __builtin_amdgcn_mfma_f32_16x16x32_bf16(a, w1, acc1, 0, 0, 0);
    acc2 = __builtin_amdgcn_mfma_f32_16x16x32_bf16(a, w2, acc2, 0, 0, 0);
    acc3 = __builtin_amdgcn_mfma_f32_16x16x32_bf16(a, w3, acc3, 0, 0, 0);
    ap += ast; wp += wst;
  }
  // cross-wave K-reduce via LDS: slot (m, w, lane)
  *reinterpret_cast<f32x4*>(&red[(((size_t)0*4 + wv)*64 + lane)*4]) = acc0;
  *reinterpret_cast<f32x4*>(&red[(((size_t)1*4 + wv)*64 + lane)*4]) = acc1;
  *reinterpret_cast<f32x4*>(&red[(((size_t)2*4 + wv)*64 + lane)*4]) = acc2;
  *reinterpret_cast<f32x4*>(&red[(((size_t)3*4 + wv)*64 + lane)*4]) = acc3;
  __syncthreads();
  // wave wv finalizes n-subtile m = wv
  f32x4 s{0.f,0.f,0.f,0.f};
  #pragma unroll
  for (int w = 0; w < 4; w++) {
    f32x4 p = *reinterpret_cast<f32x4*>(&red[(((size_t)wv*4 + w)*64 + lane)*4]);
    s[0] += p[0]; s[1] += p[1]; s[2] += p[2]; s[3] += p[3];
  }
  int row0 = bx*16 + (lane >> 4)*4;
  int j = by*64 + wv*16 + (lane & 15);
  float bj = (j < NH) ? bias[j] : 0.f;
  #pragma unroll
  for (int r = 0; r < 4; r++) {
    float v = s[r] + bj;
    v = v > 0.f ? v : 0.f;
    if (j < 608) hout[(size_t)(row0 + r)*HP + j] = f2bf(v);
  }
}

// ---------------- the single fused kernel ----------------
__global__ __launch_bounds__(256, 4)
void k_all(const int* __restrict__ px, const int* __restrict__ hx,
           const int* __restrict__ pwi, const int* __restrict__ prel,
           const int* __restrict__ hwi, const int* __restrict__ hrel,
           const float* __restrict__ Etab, const float* __restrict__ Wenc,
           const float* __restrict__ W0w, const float* __restrict__ W0b,
           const float* __restrict__ W1w, const float* __restrict__ W1b,
           const float* __restrict__ W2w, const float* __restrict__ W2b,
           const float* __restrict__ Woutw, const float* __restrict__ Woutb,
           float* __restrict__ rep, float* __restrict__ root,
           ushort* __restrict__ Wbf, ushort* __restrict__ W0S,
           ushort* __restrict__ W1S, ushort* __restrict__ W2S,
           ushort* __restrict__ Xsw, ushort* __restrict__ h1,
           ushort* __restrict__ h2, ushort* __restrict__ h3,
           unsigned* cnt, float* __restrict__ outp) {
  __shared__ __align__(16) ushort hS[64*TS];   // 41,984 B (tree; FC reduce reuses)
  __shared__ int xsh[64];
  __shared__ int wish[64];
  __shared__ int relsh[64];
  const int tid = threadIdx.x;
  unsigned bar = 0;

  // ===== S0: weight swizzles (tree Wbf + FC W0S/W1S/W2S) =====
  for (int t0 = blockIdx.x*256 + tid; t0 < SETUP_ITEMS; t0 += NBLK*256) {
    int t = t0;
    if (t < NSWZ) {
      int lane = t & 63, rest = t >> 6;
      int ksi = rest % 10, rnt = rest / 10, nt = rnt % 20, r = rnt / 20;
      int f = nt*16 + (lane & 15), e0 = ksi*32 + (lane >> 4)*8;
      ushort v[8];
      #pragma unroll
      for (int j = 0; j < 8; j++) {
        int e = e0 + j;
        v[j] = (f < NE && e < NE) ? f2bf(Wenc[((size_t)r*NE + f)*NE + e]) : (ushort)0;
      }
      *reinterpret_cast<int4*>(&Wbf[(size_t)t*8]) = *reinterpret_cast<const int4*>(v);
    } else {
      t -= NSWZ;
      const float* W; ushort* D; int K;
      if (t < N0S)            { W = W0w; D = W0S; K = 6*NE; }
      else { t -= N0S;
        if (t < N1S)          { W = W1w; D = W1S; K = NH; }
        else { t -= N1S;        W = W2w; D = W2S; K = NH; } }
      int lane = t & 63, g = t >> 6;
      int jt = g % NJT, kt = g / NJT;
      int j  = jt*16 + (lane & 15);
      int kb = kt*32 + (lane >> 4)*8;
      ushort v[8];
      #pragma unroll
      for (int i = 0; i < 8; i++) {
        int k = kb + i;
        v[i] = (j < NH && k < K) ? f2bf(W[(size_t)j*K + k]) : (ushort)0;
      }
      *reinterpret_cast<int4*>(&D[(size_t)t*8]) = *reinterpret_cast<const int4*>(v);
    }
  }
  bar += NBLK; gridbar(cnt, bar);

  // ===== S1: tree (one (s,b) per block) =====
  {
    const int sb = blockIdx.x;
    const int s = sb >> 8, b = sb & 255;

    if (tid < 64) xsh[tid] = ((s ? hx : px) + b*NS)[tid];
    else if (tid < 128) wish[tid-64] = ((s ? hwi : pwi) + b*NN)[tid-64];
    else if (tid < 192) relsh[tid-128] = ((s ? hrel : prel) + b*NN)[tid-128];
    __syncthreads();

    for (int e = tid; e < NE; e += 256) {
      float acc = 0.f;
      #pragma unroll 8
      for (int j = 0; j < NS; j++) acc += Etab[(size_t)xsh[j]*NE + e];
      rep[(size_t)sb*NE + e] = acc;
    }
    for (int flat = tid; flat < 64*75; flat += 256) {
      int n = flat / 75, c = flat % 75;
      int w = wish[n];
      float4 v;
      if (w < 0) v = float4{1.f,1.f,1.f,1.f};
      else v = *reinterpret_cast<const float4*>(&Etab[(size_t)xsh[w]*NE + c*4]);
      ushort4 o; o.x = f2bf(v.x); o.y = f2bf(v.y); o.z = f2bf(v.z); o.w = f2bf(v.w);
      *reinterpret_cast<ushort4*>(&hS[n*TS + c*4]) = o;
    }
    for (int z = tid; z < 64*10; z += 256) {
      int row = z / 10, cc = z % 10;
      *reinterpret_cast<unsigned*>(&hS[row*TS + 300 + cc*2]) = 0u;
    }
    __syncthreads();

    const int wave = tid >> 6, lane = tid & 63;
    const int mrow = lane & 15, quad = lane >> 4;

    // Phase L3
    {
      const int mb0 = 21, mb1 = 37, mb2 = 53;
      bf16x8 af[3][10];
      #pragma unroll
      for (int ks = 0; ks < 10; ks++) {
        af[0][ks] = *reinterpret_cast<const bf16x8*>(&hS[(mb0+mrow)*TS + ks*32 + quad*8]);
        af[1][ks] = *reinterpret_cast<const bf16x8*>(&hS[(mb1+mrow)*TS + ks*32 + quad*8]);
        int r2 = min(mb2+mrow, 63);
        af[2][ks] = *reinterpret_cast<const bf16x8*>(&hS[r2*TS + ks*32 + quad*8]);
      }
      __syncthreads();
      for (int pr = wave; pr < 57; pr += 4) {
        int r = pr / 19, nt = pr % 19;
        const ushort* Wb = &Wbf[(size_t)((r*20 + nt)*10)*64*8];
        f32x4 acc0 = f32x4{0.f,0.f,0.f,0.f};
        f32x4 acc1 = f32x4{0.f,0.f,0.f,0.f};
        f32x4 acc2 = f32x4{0.f,0.f,0.f,0.f};
        #pragma unroll
        for (int ks = 0; ks < 10; ks++) {
          bf16x8 bf = *reinterpret_cast<const bf16x8*>(&Wb[((size_t)ks*64 + lane)*8]);
          acc0 = __builtin_amdgcn_mfma_f32_16x16x32_bf16(af[0][ks], bf, acc0, 0, 0, 0);
          acc1 = __builtin_amdgcn_mfma_f32_16x16x32_bf16(af[1][ks], bf, acc1, 0, 0, 0);
          acc2 = __builtin_amdgcn_mfma_f32_16x16x32_bf16(af[2][ks], bf, acc2, 0, 0, 0);
        }
        int f = nt*16 + mrow;
        if (f < NE) {
          #pragma unroll
          for (int reg = 0; reg < 4; reg++) {
            int m = quad*4 + reg;
            int c0 = mb0 + m, c1 = mb1 + m, c2 = mb2 + m;
            if (relsh[c0] == r) hS[c0*TS + f] = f2bf(acc0[reg]);
            if (relsh[c1] == r) hS[c1*TS + f] = f2bf(acc1[reg]);
            if (c2 < 64 && relsh[c2] == r) hS[c2*TS + f] = f2bf(acc2[reg]);
          }
        }
      }
      __syncthreads();
      for (int f = tid; f < NE; f += 256) {
        #pragma unroll
        for (int p = 5; p <= 15; p++) {
          int nc = (p == 15) ? 3 : 4;
          float sum = 0.f;
          for (int j = 0; j < nc; j++) sum += bf2f(hS[(4*p+1+j)*TS + f]);
          float v = bf2f(hS[p*TS + f]) * sum * (1.0f/(float)nc);
          hS[p*TS + f] = f2bf(v > 0.f ? v : 0.f);
        }
      }
      __syncthreads();
    }
    // Phase L2
    {
      bf16x8 af[10];
      #pragma unroll
      for (int ks = 0; ks < 10; ks++)
        af[ks] = *reinterpret_cast<const bf16x8*>(&hS[(5+mrow)*TS + ks*32 + quad*8]);
      __syncthreads();
      for (int pr = wave; pr < 57; pr += 4) {
        int r = pr / 19, nt = pr % 19;
        const ushort* Wb = &Wbf[(size_t)((r*20 + nt)*10)*64*8];
        f32x4 acc = f32x4{0.f,0.f,0.f,0.f};
        #pragma unroll
        for (int ks = 0; ks < 10; ks++) {
          bf16x8 bf = *reinterpret_cast<const bf16x8*>(&Wb[((size_t)ks*64 + lane)*8]);
          acc = __builtin_amdgcn_mfma_f32_16x16x32_bf16(af[ks], bf, acc, 0, 0, 0);
        }
        int f = nt*16 + mrow;
        if (f < NE) {
          #pragma unroll
          for (int reg = 0; reg < 4; reg++) {
            int c = 5 + quad*4 + reg;
            if (relsh[c] == r) hS[c*TS + f] = f2bf(acc[reg]);
          }
        }
      }
      __syncthreads();
      for (int f = tid; f < NE; f += 256) {
        #pragma unroll
        for (int p = 1; p <= 4; p++) {
          float sum = 0.f;
          #pragma unroll
          for (int j = 0; j < 4; j++) sum += bf2f(hS[(4*p+1+j)*TS + f]);
          float v = bf2f(hS[p*TS + f]) * sum * 0.25f;
          hS[p*TS + f] = f2bf(v > 0.f ? v : 0.f);
        }
      }
      __syncthreads();
    }
    // Phase L1
    {
      bool rp0 = (relsh[1]==0)|(relsh[2]==0)|(relsh[3]==0)|(relsh[4]==0);
      bool rp1 = (relsh[1]==1)|(relsh[2]==1)|(relsh[3]==1)|(relsh[4]==1);
      bool rp2 = (relsh[1]==2)|(relsh[2]==2)|(relsh[3]==2)|(relsh[4]==2);
      bf16x8 af[10];
      #pragma unroll
      for (int ks = 0; ks < 10; ks++)
        af[ks] = *reinterpret_cast<const bf16x8*>(&hS[(1+min(mrow,3))*TS + ks*32 + quad*8]);
      __syncthreads();
      for (int pr = wave; pr < 57; pr += 4) {
        int r = pr / 19, nt = pr % 19;
        if ((r==0 && !rp0) || (r==1 && !rp1) || (r==2 && !rp2)) continue;
        const ushort* Wb = &Wbf[(size_t)((r*20 + nt)*10)*64*8];
        f32x4 acc = f32x4{0.f,0.f,0.f,0.f};
        #pragma unroll
        for (int ks = 0; ks < 10; ks++) {
          bf16x8 bf = *reinterpret_cast<const bf16x8*>(&Wb[((size_t)ks*64 + lane)*8]);
          acc = __builtin_amdgcn_mfma_f32_16x16x32_bf16(af[ks], bf, acc, 0, 0, 0);
        }
        int f = nt*16 + mrow;
        if (f < NE) {
          #pragma unroll
          for (int reg = 0; reg < 4; reg++) {
            int m = quad*4 + reg;
            if (m < 4 && relsh[1+m] == r) hS[(1+m)*TS + f] = f2bf(acc[reg]);
          }
        }
      }
      __syncthreads();
      for (int f = tid; f < NE; f += 256) {
        float sum = 0.f;
        #pragma unroll
        for (int c = 1; c <= 4; c++) sum += bf2f(hS[c*TS + f]);
        float v = bf2f(hS[0*TS + f]) * sum * 0.25f;
        root[(size_t)sb*NE + f] = v > 0.f ? v : 0.f;
      }
    }
  }
  bar += NBLK; gridbar(cnt, bar);

  // ===== S2: feature build (A-frag swizzled bf16) =====
  {
    int t = blockIdx.x*256 + tid;
    if (t < FEAT_ITEMS) {
      int lane = t & 63, g = t >> 6;
      int mt = g % 16, kt = g / 16;
      int b  = mt*16 + (lane & 15);
      int kb = kt*32 + (lane >> 4)*8;
      const float* rp = rep  + (size_t)b*NE;
      const float* rh = rep  + (size_t)(NB+b)*NE;
      const float* tp = root + (size_t)b*NE;
      const float* th = root + (size_t)(NB+b)*NE;
      ushort v[8];
      #pragma unroll
      for (int i = 0; i < 8; i++) {
        int k = kb + i;
        float x = 0.f;
        if (k < 6*NE) {
          int seg = k / NE, e = k - seg*NE;
          switch (seg) {
            case 0:  x = rp[e]; break;
            case 1:  x = rh[e]; break;
            case 2:  x = rp[e] - rh[e]; break;
            case 3:  x = rp[e] * rh[e]; break;
            case 4:  x = tp[e] - th[e]; break;
            default: x = tp[e] * th[e]; break;
          }
        }
        v[i] = f2bf(x);
      }
      *reinterpret_cast<int4*>(&Xsw[(size_t)t*8]) = *reinterpret_cast<const int4*>(v);
    }
  }
  bar += NBLK; gridbar(cnt, bar);

  // ===== S3/S4/S5: FC layers (single instantiation, runtime layer loop) =====
  float* red = reinterpret_cast<float*>(hS);   // 16 KB reduce buffer (hS reuse)
  for (int l = 0; l < 3; l++) {
    const ushort* Arm = (l == 0) ? nullptr : (l == 1 ? h1 : h2);
    const ushort* Xs  = (l == 0) ? Xsw : nullptr;
    const ushort* Wsw = (l == 0) ? W0S : (l == 1 ? W1S : W2S);
    const float*  bia = (l == 0) ? W0b : (l == 1 ? W1b : W2b);
    ushort*       ho  = (l == 0) ? h1  : (l == 1 ? h2  : h3);
    int nkt = (l == 0) ? KT0 : KT1;
    fc_layer(Arm, Xs, Wsw, bia, ho, nkt, red);
    bar += NBLK; gridbar(cnt, bar);
  }

  // ===== S6: 600 -> 3 output =====
  if (blockIdx.x < NB && tid < 64) {
    int b = blockIdx.x;
    float a0 = 0.f, a1 = 0.f, a2 = 0.f;
    for (int k = tid; k < NH; k += 64) {
      float xv = bf2f(h3[(size_t)b*HP + k]);
      a0 += xv * Woutw[k];
      a1 += xv * Woutw[NH + k];
      a2 += xv * Woutw[2*NH + k];
    }
    #pragma unroll
    for (int off = 32; off > 0; off >>= 1) {
      a0 += __shfl_down(a0, off, 64);
      a1 += __shfl_down(a1, off, 64);
      a2 += __shfl_down(a2, off, 64);
    }
    if (tid == 0) {
      outp[b*3 + 0] = a0 + Woutb[0];
      outp[b*3 + 1] = a1 + Woutb[1];
      outp[b*3 + 2] = a2 + Woutb[2];
    }
  }
}

// ---------------- launch ----------------
extern "C" void kernel_launch(void* const* d_in, const int* in_sizes, int n_in,
                              void* d_out, int out_size, void* d_ws, size_t ws_size,
                              hipStream_t stream) {
  const int*   px    = (const int*)d_in[0];
  const int*   hx    = (const int*)d_in[1];
  const int*   pwi   = (const int*)d_in[2];
  const int*   prel  = (const int*)d_in[3];
  const int*   hwi   = (const int*)d_in[4];
  const int*   hrel  = (const int*)d_in[5];
  // d_in[6]=parent, d_in[7]=level: fixed 4-ary tree, hardcoded
  const float* Etab  = (const float*)d_in[8];
  const float* Wenc  = (const float*)d_in[9];
  const float* W0w   = (const float*)d_in[10];
  const float* W0b   = (const float*)d_in[11];
  const float* W1w   = (const float*)d_in[12];
  const float* W1b   = (const float*)d_in[13];
  const float* W2w   = (const float*)d_in[14];
  const float* W2b   = (const float*)d_in[15];
  const float* Woutw = (const float*)d_in[16];
  const float* Woutb = (const float*)d_in[17];

  float* ws   = (float*)d_ws;
  float*  rep  = ws + OFF_REP;
  float*  root = ws + OFF_ROOT;
  ushort* Wbf  = (ushort*)(ws + OFF_WBF);
  ushort* W0S  = (ushort*)(ws + OFF_W0S);
  ushort* W1S  = (ushort*)(ws + OFF_W1S);
  ushort* W2S  = (ushort*)(ws + OFF_W2S);
  ushort* Xsw  = (ushort*)(ws + OFF_XSW);
  ushort* h1   = (ushort*)(ws + OFF_H1);
  ushort* h2   = (ushort*)(ws + OFF_H2);
  ushort* h3   = (ushort*)(ws + OFF_H3);
  unsigned* cnt = (unsigned*)(ws + OFF_CNT);
  float* outp = (float*)d_out;

  hipMemsetAsync(cnt, 0, sizeof(unsigned), stream);
  k_all<<<dim3(NBLK), dim3(256), 0, stream>>>(
      px, hx, pwi, prel, hwi, hrel, Etab, Wenc,
      W0w, W0b, W1w, W1b, W2w, W2b, Woutw, Woutb,
      rep, root, Wbf, W0S, W1S, W2S, Xsw, h1, h2, h3, cnt, outp);
}

// Round 6
// 385.975 us; speedup vs baseline: 1.6140x; 1.6140x over previous
//
#include <hip/hip_runtime.h>

constexpr int NB = 256;   // batch
constexpr int NS = 64;    // seq len
constexpr int NN = 64;    // tree nodes
constexpr int NE = 300;   // embedding dim
constexpr int NH = 600;   // hidden dim

typedef __attribute__((ext_vector_type(8))) short bf16x8;
typedef __attribute__((ext_vector_type(4))) float f32x4;

// FC GEMM geometry: K padded to 32, N padded to 640 (40 j-tiles of 16)
constexpr int KT0 = 57;   // ceil(1800/32)
constexpr int KT1 = 19;   // ceil(600/32)
constexpr int NJT = 40;   // 640/16 j-tiles

// ---------------- workspace layout (float-indexed) ----------------
constexpr size_t OFF_REP = 0;                           // [2][NB][NE] fp32
constexpr size_t SZ_REP  = (size_t)2*NB*NE;
constexpr size_t OFF_ROOT= OFF_REP + SZ_REP;            // [2][NB][NE] fp32
constexpr size_t OFF_WBF = OFF_ROOT + SZ_REP;           // tree W_enc bf16 B-frag swizzled
constexpr size_t SZ_WBF  = (size_t)3*20*10*64*8/2;      // 153,600 floats
constexpr size_t OFF_W0S = OFF_WBF + SZ_WBF;            // W0 bf16 B-frag swizzled
constexpr size_t SZ_W0S  = (size_t)KT0*NJT*64*8/2;
constexpr size_t OFF_W1S = OFF_W0S + SZ_W0S;
constexpr size_t SZ_W1S  = (size_t)KT1*NJT*64*8/2;
constexpr size_t OFF_W2S = OFF_W1S + SZ_W1S;

__device__ __forceinline__ ushort f2bf(float x) {
  unsigned u = __float_as_uint(x);
  unsigned r = (u + 0x7FFFu + ((u >> 16) & 1u)) >> 16;   // RNE
  return (ushort)r;
}
__device__ __forceinline__ float bf2f(ushort u) {
  return __uint_as_float(((unsigned)u) << 16);
}

// ---------------- k_setup: tree-W swizzle + FC weight bf16 B-frag swizzles ---
constexpr int NSWZ = 3*20*10*64;          // 38400 tree lane-frags
constexpr int N0S  = KT0*NJT*64;          // 145,920
constexpr int N1S  = KT1*NJT*64;          // 48,640
constexpr int SETUP_ITEMS  = NSWZ + N0S + 2*N1S;   // 281,600
constexpr int SETUP_BLOCKS = SETUP_ITEMS/256;      // 1100 exactly

__global__ __launch_bounds__(256)
void k_setup(const float* __restrict__ Wenc, const float* __restrict__ W0,
             const float* __restrict__ W1, const float* __restrict__ W2,
             ushort* __restrict__ Wbf, ushort* __restrict__ W0S,
             ushort* __restrict__ W1S, ushort* __restrict__ W2S) {
  int t = blockIdx.x*256 + threadIdx.x;
  if (t < NSWZ) {
    int lane = t & 63, rest = t >> 6;
    int ksi = rest % 10, rnt = rest / 10, nt = rnt % 20, r = rnt / 20;
    int f = nt*16 + (lane & 15), e0 = ksi*32 + (lane >> 4)*8;
    ushort v[8];
    #pragma unroll
    for (int j = 0; j < 8; j++) {
      int e = e0 + j;
      v[j] = (f < NE && e < NE) ? f2bf(Wenc[((size_t)r*NE + f)*NE + e]) : (ushort)0;
    }
    *reinterpret_cast<int4*>(&Wbf[(size_t)t*8]) = *reinterpret_cast<const int4*>(v);
    return;
  }
  t -= NSWZ;
  const float* W; ushort* D; int K;
  if (t < N0S)              { W = W0; D = W0S; K = 6*NE; }
  else { t -= N0S;
    if (t < N1S)            { W = W1; D = W1S; K = NH; }
    else { t -= N1S;          W = W2; D = W2S; K = NH; } }
  int lane = t & 63, g = t >> 6;
  int jt = g % NJT, kt = g / NJT;
  int j  = jt*16 + (lane & 15);
  int kb = kt*32 + (lane >> 4)*8;
  ushort v[8];
  #pragma unroll
  for (int i = 0; i < 8; i++) {
    int k = kb + i;
    v[i] = (j < NH && k < K) ? f2bf(W[(size_t)j*K + k]) : (ushort)0;
  }
  *reinterpret_cast<int4*>(&D[(size_t)t*8]) = *reinterpret_cast<const int4*>(v);
}

// ---------------- k_tree: whole tree for one (s,b) per block (R2, verified) --
constexpr int TS = 328;   // row stride (ushorts)

__global__ __launch_bounds__(256)
void k_tree(const int* __restrict__ px, const int* __restrict__ hx,
            const int* __restrict__ pwi, const int* __restrict__ prel,
            const int* __restrict__ hwi, const int* __restrict__ hrel,
            const float* __restrict__ Etab, const ushort* __restrict__ Wbf,
            float* __restrict__ rep, float* __restrict__ root) {
  __shared__ __align__(16) ushort hS[64*TS];   // 41,984 B
  __shared__ int xsh[64];
  __shared__ int wish[64];
  __shared__ int relsh[64];
  const int sb = blockIdx.x;
  const int s = sb >> 8, b = sb & 255;
  const int tid = threadIdx.x;

  if (tid < 64) xsh[tid] = ((s ? hx : px) + b*NS)[tid];
  else if (tid < 128) wish[tid-64] = ((s ? hwi : pwi) + b*NN)[tid-64];
  else if (tid < 192) relsh[tid-128] = ((s ? hrel : prel) + b*NN)[tid-128];
  __syncthreads();

  for (int e = tid; e < NE; e += 256) {
    float acc = 0.f;
    #pragma unroll 8
    for (int j = 0; j < NS; j++) acc += Etab[(size_t)xsh[j]*NE + e];
    rep[(size_t)sb*NE + e] = acc;
  }
  for (int flat = tid; flat < 64*75; flat += 256) {
    int n = flat / 75, c = flat % 75;
    int w = wish[n];
    float4 v;
    if (w < 0) v = float4{1.f,1.f,1.f,1.f};
    else v = *reinterpret_cast<const float4*>(&Etab[(size_t)xsh[w]*NE + c*4]);
    ushort4 o; o.x = f2bf(v.x); o.y = f2bf(v.y); o.z = f2bf(v.z); o.w = f2bf(v.w);
    *reinterpret_cast<ushort4*>(&hS[n*TS + c*4]) = o;
  }
  for (int z = tid; z < 64*10; z += 256) {
    int row = z / 10, cc = z % 10;
    *reinterpret_cast<unsigned*>(&hS[row*TS + 300 + cc*2]) = 0u;
  }
  __syncthreads();

  const int wave = tid >> 6, lane = tid & 63;
  const int mrow = lane & 15, quad = lane >> 4;

  // Phase L3
  {
    const int mb0 = 21, mb1 = 37, mb2 = 53;
    bf16x8 af[3][10];
    #pragma unroll
    for (int ks = 0; ks < 10; ks++) {
      af[0][ks] = *reinterpret_cast<const bf16x8*>(&hS[(mb0+mrow)*TS + ks*32 + quad*8]);
      af[1][ks] = *reinterpret_cast<const bf16x8*>(&hS[(mb1+mrow)*TS + ks*32 + quad*8]);
      int r2 = min(mb2+mrow, 63);
      af[2][ks] = *reinterpret_cast<const bf16x8*>(&hS[r2*TS + ks*32 + quad*8]);
    }
    __syncthreads();
    for (int pr = wave; pr < 57; pr += 4) {
      int r = pr / 19, nt = pr % 19;
      const ushort* Wb = &Wbf[(size_t)((r*20 + nt)*10)*64*8];
      f32x4 acc0 = f32x4{0.f,0.f,0.f,0.f};
      f32x4 acc1 = f32x4{0.f,0.f,0.f,0.f};
      f32x4 acc2 = f32x4{0.f,0.f,0.f,0.f};
      #pragma unroll
      for (int ks = 0; ks < 10; ks++) {
        bf16x8 bf = *reinterpret_cast<const bf16x8*>(&Wb[((size_t)ks*64 + lane)*8]);
        acc0 = __builtin_amdgcn_mfma_f32_16x16x32_bf16(af[0][ks], bf, acc0, 0, 0, 0);
        acc1 = __builtin_amdgcn_mfma_f32_16x16x32_bf16(af[1][ks], bf, acc1, 0, 0, 0);
        acc2 = __builtin_amdgcn_mfma_f32_16x16x32_bf16(af[2][ks], bf, acc2, 0, 0, 0);
      }
      int f = nt*16 + mrow;
      if (f < NE) {
        #pragma unroll
        for (int reg = 0; reg < 4; reg++) {
          int m = quad*4 + reg;
          int c0 = mb0 + m, c1 = mb1 + m, c2 = mb2 + m;
          if (relsh[c0] == r) hS[c0*TS + f] = f2bf(acc0[reg]);
          if (relsh[c1] == r) hS[c1*TS + f] = f2bf(acc1[reg]);
          if (c2 < 64 && relsh[c2] == r) hS[c2*TS + f] = f2bf(acc2[reg]);
        }
      }
    }
    __syncthreads();
    for (int f = tid; f < NE; f += 256) {
      #pragma unroll
      for (int p = 5; p <= 15; p++) {
        int nc = (p == 15) ? 3 : 4;
        float sum = 0.f;
        for (int j = 0; j < nc; j++) sum += bf2f(hS[(4*p+1+j)*TS + f]);
        float v = bf2f(hS[p*TS + f]) * sum * (1.0f/(float)nc);
        hS[p*TS + f] = f2bf(v > 0.f ? v : 0.f);
      }
    }
    __syncthreads();
  }
  // Phase L2
  {
    bf16x8 af[10];
    #pragma unroll
    for (int ks = 0; ks < 10; ks++)
      af[ks] = *reinterpret_cast<const bf16x8*>(&hS[(5+mrow)*TS + ks*32 + quad*8]);
    __syncthreads();
    for (int pr = wave; pr < 57; pr += 4) {
      int r = pr / 19, nt = pr % 19;
      const ushort* Wb = &Wbf[(size_t)((r*20 + nt)*10)*64*8];
      f32x4 acc = f32x4{0.f,0.f,0.f,0.f};
      #pragma unroll
      for (int ks = 0; ks < 10; ks++) {
        bf16x8 bf = *reinterpret_cast<const bf16x8*>(&Wb[((size_t)ks*64 + lane)*8]);
        acc = __builtin_amdgcn_mfma_f32_16x16x32_bf16(af[ks], bf, acc, 0, 0, 0);
      }
      int f = nt*16 + mrow;
      if (f < NE) {
        #pragma unroll
        for (int reg = 0; reg < 4; reg++) {
          int c = 5 + quad*4 + reg;
          if (relsh[c] == r) hS[c*TS + f] = f2bf(acc[reg]);
        }
      }
    }
    __syncthreads();
    for (int f = tid; f < NE; f += 256) {
      #pragma unroll
      for (int p = 1; p <= 4; p++) {
        float sum = 0.f;
        #pragma unroll
        for (int j = 0; j < 4; j++) sum += bf2f(hS[(4*p+1+j)*TS + f]);
        float v = bf2f(hS[p*TS + f]) * sum * 0.25f;
        hS[p*TS + f] = f2bf(v > 0.f ? v : 0.f);
      }
    }
    __syncthreads();
  }
  // Phase L1
  {
    bool rp0 = (relsh[1]==0)|(relsh[2]==0)|(relsh[3]==0)|(relsh[4]==0);
    bool rp1 = (relsh[1]==1)|(relsh[2]==1)|(relsh[3]==1)|(relsh[4]==1);
    bool rp2 = (relsh[1]==2)|(relsh[2]==2)|(relsh[3]==2)|(relsh[4]==2);
    bf16x8 af[10];
    #pragma unroll
    for (int ks = 0; ks < 10; ks++)
      af[ks] = *reinterpret_cast<const bf16x8*>(&hS[(1+min(mrow,3))*TS + ks*32 + quad*8]);
    __syncthreads();
    for (int pr = wave; pr < 57; pr += 4) {
      int r = pr / 19, nt = pr % 19;
      if ((r==0 && !rp0) || (r==1 && !rp1) || (r==2 && !rp2)) continue;
      const ushort* Wb = &Wbf[(size_t)((r*20 + nt)*10)*64*8];
      f32x4 acc = f32x4{0.f,0.f,0.f,0.f};
      #pragma unroll
      for (int ks = 0; ks < 10; ks++) {
        bf16x8 bf = *reinterpret_cast<const bf16x8*>(&Wb[((size_t)ks*64 + lane)*8]);
        acc = __builtin_amdgcn_mfma_f32_16x16x32_bf16(af[ks], bf, acc, 0, 0, 0);
      }
      int f = nt*16 + mrow;
      if (f < NE) {
        #pragma unroll
        for (int reg = 0; reg < 4; reg++) {
          int m = quad*4 + reg;
          if (m < 4 && relsh[1+m] == r) hS[(1+m)*TS + f] = f2bf(acc[reg]);
        }
      }
    }
    __syncthreads();
    for (int f = tid; f < NE; f += 256) {
      float sum = 0.f;
      #pragma unroll
      for (int c = 1; c <= 4; c++) sum += bf2f(hS[c*TS + f]);
      float v = bf2f(hS[0*TS + f]) * sum * 0.25f;
      root[(size_t)sb*NE + f] = v > 0.f ? v : 0.f;
    }
  }
}

// ---------------- k_tail: feat + FC0/1/2 + out, all in one block-local chain -
// 16 blocks x 512 threads (8 waves). Block owns 16 batch rows end-to-end:
// X-tile built in A-frag LDS layout (two K-halves), h1/h2/h3 ping-pong in LDS.
// Wave wv computes j-tiles [wv*5, wv*5+5) of 40. No grid barriers, no atomics.
constexpr int TB   = 16;    // batch rows per block
constexpr int HKT  = 29;    // layer-0 K-tiles per half (29+28=57)
constexpr int HSTR = 648;   // LDS h row stride (ushorts); 648*2B/4=324dw, 324%32=4 -> 2-way (free)

__global__ __launch_bounds__(512)
void k_tail(const float* __restrict__ rep, const float* __restrict__ root,
            const ushort* __restrict__ W0S, const ushort* __restrict__ W1S,
            const ushort* __restrict__ W2S,
            const float* __restrict__ b0v, const float* __restrict__ b1v,
            const float* __restrict__ b2v,
            const float* __restrict__ Woutw, const float* __restrict__ Woutb,
            float* __restrict__ outp) {
  __shared__ __align__(16) ushort XA[HKT*64*8];   // 29,696 B (X frags; h2 reuses)
  __shared__ __align__(16) ushort HB[TB*HSTR];    // 20,736 B (h1, then h3)
  const int tid = threadIdx.x;
  const int wv = tid >> 6, lane = tid & 63;
  const int b0 = blockIdx.x * TB;

  f32x4 acc[5];
  #pragma unroll
  for (int q = 0; q < 5; q++) acc[q] = f32x4{0.f,0.f,0.f,0.f};

  // ---- layer 0: K=1824 in two halves, XA rebuilt between ----
  for (int hh = 0; hh < 2; hh++) {
    const int kbase = hh * HKT;
    const int nk = hh ? (KT0 - HKT) : HKT;     // 28 : 29
    for (int it = tid; it < nk*64; it += 512) {
      int l = it & 63, ktl = it >> 6;
      int b = b0 + (l & 15);
      int kb = (kbase + ktl)*32 + (l >> 4)*8;
      const float* rp = rep  + (size_t)b*NE;
      const float* rh = rep  + (size_t)(NB+b)*NE;
      const float* tp = root + (size_t)b*NE;
      const float* th = root + (size_t)(NB+b)*NE;
      ushort v[8];
      #pragma unroll
      for (int i = 0; i < 8; i++) {
        int k = kb + i;
        float x = 0.f;
        if (k < 6*NE) {
          int seg = k / NE, e = k - seg*NE;
          switch (seg) {
            case 0:  x = rp[e]; break;
            case 1:  x = rh[e]; break;
            case 2:  x = rp[e] - rh[e]; break;
            case 3:  x = rp[e] * rh[e]; break;
            case 4:  x = tp[e] - th[e]; break;
            default: x = tp[e] * th[e]; break;
          }
        }
        v[i] = f2bf(x);
      }
      *reinterpret_cast<int4*>(&XA[(size_t)(ktl*64 + l)*8]) =
          *reinterpret_cast<const int4*>(v);
    }
    __syncthreads();
    for (int ktl = 0; ktl < nk; ktl++) {
      int kt = kbase + ktl;
      bf16x8 a = *reinterpret_cast<const bf16x8*>(&XA[(size_t)(ktl*64 + lane)*8]);
      #pragma unroll
      for (int q = 0; q < 5; q++) {
        bf16x8 w = *reinterpret_cast<const bf16x8*>(
            &W0S[((size_t)(kt*NJT + wv*5 + q)*64 + lane)*8]);
        acc[q] = __builtin_amdgcn_mfma_f32_16x16x32_bf16(a, w, acc[q], 0, 0, 0);
      }
    }
    __syncthreads();   // all XA reads done before rebuild (and before h-writes)
  }
  // epilogue: h1 -> HB (row-major, cols 600..607 zeroed for K-padding)
  {
    int r0 = (lane >> 4)*4;
    #pragma unroll
    for (int q = 0; q < 5; q++) {
      int j = (wv*5 + q)*16 + (lane & 15);
      if (j < 608) {
        float bj = (j < 600) ? b0v[j] : 0.f;
        #pragma unroll
        for (int r = 0; r < 4; r++) {
          float vv = acc[q][r] + bj;
          vv = vv > 0.f ? vv : 0.f;
          HB[(size_t)(r0 + r)*HSTR + j] = (j < 600) ? f2bf(vv) : (ushort)0;
        }
      }
    }
  }
  __syncthreads();

  // ---- layers 1 & 2: A-frags read from row-major LDS h-tile ----
  for (int l = 1; l <= 2; l++) {
    const ushort* Hs = (l == 1) ? HB : XA;
    ushort*       Hd = (l == 1) ? XA : HB;
    const ushort* Ws = (l == 1) ? W1S : W2S;
    const float*  bs = (l == 1) ? b1v : b2v;
    #pragma unroll
    for (int q = 0; q < 5; q++) acc[q] = f32x4{0.f,0.f,0.f,0.f};
    for (int kt = 0; kt < KT1; kt++) {
      bf16x8 a = *reinterpret_cast<const bf16x8*>(
          &Hs[(size_t)(lane & 15)*HSTR + kt*32 + (lane >> 4)*8]);
      #pragma unroll
      for (int q = 0; q < 5; q++) {
        bf16x8 w = *reinterpret_cast<const bf16x8*>(
            &Ws[((size_t)(kt*NJT + wv*5 + q)*64 + lane)*8]);
        acc[q] = __builtin_amdgcn_mfma_f32_16x16x32_bf16(a, w, acc[q], 0, 0, 0);
      }
    }
    // epilogue writes to Hd: Hd is dead for reads at this point (l=1: XA last
    // read in layer 0; l=2: HB last read in layer 1, guarded by loop-end sync)
    {
      int r0 = (lane >> 4)*4;
      #pragma unroll
      for (int q = 0; q < 5; q++) {
        int j = (wv*5 + q)*16 + (lane & 15);
        if (j < 608) {
          float bj = (j < 600) ? bs[j] : 0.f;
          #pragma unroll
          for (int r = 0; r < 4; r++) {
            float vv = acc[q][r] + bj;
            vv = vv > 0.f ? vv : 0.f;
            Hd[(size_t)(r0 + r)*HSTR + j] = (j < 600) ? f2bf(vv) : (ushort)0;
          }
        }
      }
    }
    __syncthreads();
  }

  // ---- out: h3 (HB) @ Wout^T + bout; 48 (row,c) dots, 8 lanes each ----
  {
    int p = tid >> 3, sub = tid & 7;
    if (p < TB*3) {
      int row = p / 3, c = p - row*3;
      float s = 0.f;
      for (int k = sub; k < NH; k += 8)
        s += bf2f(HB[(size_t)row*HSTR + k]) * Woutw[(size_t)c*NH + k];
      #pragma unroll
      for (int off = 4; off > 0; off >>= 1)
        s += __shfl_xor(s, off, 8);
      if (sub == 0) outp[(size_t)(b0 + row)*3 + c] = s + Woutb[c];
    }
  }
}

// ---------------- launch ----------------
extern "C" void kernel_launch(void* const* d_in, const int* in_sizes, int n_in,
                              void* d_out, int out_size, void* d_ws, size_t ws_size,
                              hipStream_t stream) {
  const int*   px    = (const int*)d_in[0];
  const int*   hx    = (const int*)d_in[1];
  const int*   pwi   = (const int*)d_in[2];
  const int*   prel  = (const int*)d_in[3];
  const int*   hwi   = (const int*)d_in[4];
  const int*   hrel  = (const int*)d_in[5];
  // d_in[6]=parent, d_in[7]=level: fixed 4-ary tree, hardcoded
  const float* Etab  = (const float*)d_in[8];
  const float* Wenc  = (const float*)d_in[9];
  const float* W0w   = (const float*)d_in[10];
  const float* W0b   = (const float*)d_in[11];
  const float* W1w   = (const float*)d_in[12];
  const float* W1b   = (const float*)d_in[13];
  const float* W2w   = (const float*)d_in[14];
  const float* W2b   = (const float*)d_in[15];
  const float* Woutw = (const float*)d_in[16];
  const float* Woutb = (const float*)d_in[17];

  float* ws   = (float*)d_ws;
  float*  rep  = ws + OFF_REP;
  float*  root = ws + OFF_ROOT;
  ushort* Wbf  = (ushort*)(ws + OFF_WBF);
  ushort* W0S  = (ushort*)(ws + OFF_W0S);
  ushort* W1S  = (ushort*)(ws + OFF_W1S);
  ushort* W2S  = (ushort*)(ws + OFF_W2S);
  float* outp = (float*)d_out;

  k_setup<<<dim3(SETUP_BLOCKS), dim3(256), 0, stream>>>(
      Wenc, W0w, W1w, W2w, Wbf, W0S, W1S, W2S);
  k_tree<<<dim3(2*NB), dim3(256), 0, stream>>>(
      px, hx, pwi, prel, hwi, hrel, Etab, Wbf, rep, root);
  k_tail<<<dim3(NB/TB), dim3(512), 0, stream>>>(
      rep, root, W0S, W1S, W2S, W0b, W1b, W2b, Woutw, Woutb, outp);
}

// Round 7
// 293.008 us; speedup vs baseline: 2.1261x; 1.3173x over previous
//
#include <hip/hip_runtime.h>

constexpr int NB = 256;   // batch
constexpr int NS = 64;    // seq len
constexpr int NN = 64;    // tree nodes
constexpr int NE = 300;   // embedding dim
constexpr int NH = 600;   // hidden dim

typedef __attribute__((ext_vector_type(8))) short bf16x8;
typedef __attribute__((ext_vector_type(4))) float f32x4;

// FC GEMM geometry: K padded to 32, N padded to 640 (40 j-tiles of 16)
constexpr int KT0 = 57;   // ceil(1800/32)
constexpr int KT1 = 19;   // ceil(600/32)
constexpr int NJT = 40;   // 640/16 j-tiles
constexpr int HP  = 640;  // h row stride in ushorts (cols 600..607 zeroed)

// ---------------- workspace layout (float-indexed) ----------------
constexpr size_t OFF_REP = 0;                           // [2][NB][NE] fp32
constexpr size_t SZ_REP  = (size_t)2*NB*NE;
constexpr size_t OFF_ROOT= OFF_REP + SZ_REP;            // [2][NB][NE] fp32
constexpr size_t OFF_WBF = OFF_ROOT + SZ_REP;           // tree W_enc bf16 B-frag swizzled
constexpr size_t SZ_WBF  = (size_t)3*20*10*64*8/2;      // 153,600 floats
constexpr size_t OFF_W0S = OFF_WBF + SZ_WBF;            // W0 bf16 B-frag swizzled
constexpr size_t SZ_W0S  = (size_t)KT0*NJT*64*8/2;
constexpr size_t OFF_W1S = OFF_W0S + SZ_W0S;
constexpr size_t SZ_W1S  = (size_t)KT1*NJT*64*8/2;
constexpr size_t OFF_W2S = OFF_W1S + SZ_W1S;
constexpr size_t OFF_XSW = OFF_W2S + SZ_W1S;            // X bf16 A-frag swizzled
constexpr size_t SZ_XSW  = (size_t)KT0*16*64*8/2;
constexpr size_t OFF_H1  = OFF_XSW + SZ_XSW;            // h bf16 [NB][HP]
constexpr size_t SZ_H    = (size_t)NB*HP/2;
constexpr size_t OFF_H2  = OFF_H1 + SZ_H;
constexpr size_t OFF_H3  = OFF_H2 + SZ_H;

__device__ __forceinline__ ushort f2bf(float x) {
  unsigned u = __float_as_uint(x);
  unsigned r = (u + 0x7FFFu + ((u >> 16) & 1u)) >> 16;   // RNE
  return (ushort)r;
}
__device__ __forceinline__ float bf2f(ushort u) {
  return __uint_as_float(((unsigned)u) << 16);
}

// ---------------- k_setup: tree-W swizzle + FC weight bf16 B-frag swizzles ---
constexpr int NSWZ = 3*20*10*64;          // 38400 tree lane-frags
constexpr int N0S  = KT0*NJT*64;          // 145,920
constexpr int N1S  = KT1*NJT*64;          // 48,640
constexpr int SETUP_ITEMS  = NSWZ + N0S + 2*N1S;   // 281,600
constexpr int SETUP_BLOCKS = SETUP_ITEMS/256;      // 1100 exactly

__global__ __launch_bounds__(256)
void k_setup(const float* __restrict__ Wenc, const float* __restrict__ W0,
             const float* __restrict__ W1, const float* __restrict__ W2,
             ushort* __restrict__ Wbf, ushort* __restrict__ W0S,
             ushort* __restrict__ W1S, ushort* __restrict__ W2S) {
  int t = blockIdx.x*256 + threadIdx.x;
  if (t < NSWZ) {
    int lane = t & 63, rest = t >> 6;
    int ksi = rest % 10, rnt = rest / 10, nt = rnt % 20, r = rnt / 20;
    int f = nt*16 + (lane & 15), e0 = ksi*32 + (lane >> 4)*8;
    ushort v[8];
    #pragma unroll
    for (int j = 0; j < 8; j++) {
      int e = e0 + j;
      v[j] = (f < NE && e < NE) ? f2bf(Wenc[((size_t)r*NE + f)*NE + e]) : (ushort)0;
    }
    *reinterpret_cast<int4*>(&Wbf[(size_t)t*8]) = *reinterpret_cast<const int4*>(v);
    return;
  }
  t -= NSWZ;
  const float* W; ushort* D; int K;
  if (t < N0S)              { W = W0; D = W0S; K = 6*NE; }
  else { t -= N0S;
    if (t < N1S)            { W = W1; D = W1S; K = NH; }
    else { t -= N1S;          W = W2; D = W2S; K = NH; } }
  int lane = t & 63, g = t >> 6;
  int jt = g % NJT, kt = g / NJT;
  int j  = jt*16 + (lane & 15);
  int kb = kt*32 + (lane >> 4)*8;
  ushort v[8];
  #pragma unroll
  for (int i = 0; i < 8; i++) {
    int k = kb + i;
    v[i] = (j < NH && k < K) ? f2bf(W[(size_t)j*K + k]) : (ushort)0;
  }
  *reinterpret_cast<int4*>(&D[(size_t)t*8]) = *reinterpret_cast<const int4*>(v);
}

// ---------------- k_tree: whole tree for one (s,b) per block (R2, verified) --
constexpr int TS = 328;   // row stride (ushorts)

__global__ __launch_bounds__(256)
void k_tree(const int* __restrict__ px, const int* __restrict__ hx,
            const int* __restrict__ pwi, const int* __restrict__ prel,
            const int* __restrict__ hwi, const int* __restrict__ hrel,
            const float* __restrict__ Etab, const ushort* __restrict__ Wbf,
            float* __restrict__ rep, float* __restrict__ root) {
  __shared__ __align__(16) ushort hS[64*TS];   // 41,984 B
  __shared__ int xsh[64];
  __shared__ int wish[64];
  __shared__ int relsh[64];
  const int sb = blockIdx.x;
  const int s = sb >> 8, b = sb & 255;
  const int tid = threadIdx.x;

  if (tid < 64) xsh[tid] = ((s ? hx : px) + b*NS)[tid];
  else if (tid < 128) wish[tid-64] = ((s ? hwi : pwi) + b*NN)[tid-64];
  else if (tid < 192) relsh[tid-128] = ((s ? hrel : prel) + b*NN)[tid-128];
  __syncthreads();

  for (int e = tid; e < NE; e += 256) {
    float acc = 0.f;
    #pragma unroll 8
    for (int j = 0; j < NS; j++) acc += Etab[(size_t)xsh[j]*NE + e];
    rep[(size_t)sb*NE + e] = acc;
  }
  for (int flat = tid; flat < 64*75; flat += 256) {
    int n = flat / 75, c = flat % 75;
    int w = wish[n];
    float4 v;
    if (w < 0) v = float4{1.f,1.f,1.f,1.f};
    else v = *reinterpret_cast<const float4*>(&Etab[(size_t)xsh[w]*NE + c*4]);
    ushort4 o; o.x = f2bf(v.x); o.y = f2bf(v.y); o.z = f2bf(v.z); o.w = f2bf(v.w);
    *reinterpret_cast<ushort4*>(&hS[n*TS + c*4]) = o;
  }
  for (int z = tid; z < 64*10; z += 256) {
    int row = z / 10, cc = z % 10;
    *reinterpret_cast<unsigned*>(&hS[row*TS + 300 + cc*2]) = 0u;
  }
  __syncthreads();

  const int wave = tid >> 6, lane = tid & 63;
  const int mrow = lane & 15, quad = lane >> 4;

  // Phase L3
  {
    const int mb0 = 21, mb1 = 37, mb2 = 53;
    bf16x8 af[3][10];
    #pragma unroll
    for (int ks = 0; ks < 10; ks++) {
      af[0][ks] = *reinterpret_cast<const bf16x8*>(&hS[(mb0+mrow)*TS + ks*32 + quad*8]);
      af[1][ks] = *reinterpret_cast<const bf16x8*>(&hS[(mb1+mrow)*TS + ks*32 + quad*8]);
      int r2 = min(mb2+mrow, 63);
      af[2][ks] = *reinterpret_cast<const bf16x8*>(&hS[r2*TS + ks*32 + quad*8]);
    }
    __syncthreads();
    for (int pr = wave; pr < 57; pr += 4) {
      int r = pr / 19, nt = pr % 19;
      const ushort* Wb = &Wbf[(size_t)((r*20 + nt)*10)*64*8];
      f32x4 acc0 = f32x4{0.f,0.f,0.f,0.f};
      f32x4 acc1 = f32x4{0.f,0.f,0.f,0.f};
      f32x4 acc2 = f32x4{0.f,0.f,0.f,0.f};
      #pragma unroll
      for (int ks = 0; ks < 10; ks++) {
        bf16x8 bf = *reinterpret_cast<const bf16x8*>(&Wb[((size_t)ks*64 + lane)*8]);
        acc0 = __builtin_amdgcn_mfma_f32_16x16x32_bf16(af[0][ks], bf, acc0, 0, 0, 0);
        acc1 = __builtin_amdgcn_mfma_f32_16x16x32_bf16(af[1][ks], bf, acc1, 0, 0, 0);
        acc2 = __builtin_amdgcn_mfma_f32_16x16x32_bf16(af[2][ks], bf, acc2, 0, 0, 0);
      }
      int f = nt*16 + mrow;
      if (f < NE) {
        #pragma unroll
        for (int reg = 0; reg < 4; reg++) {
          int m = quad*4 + reg;
          int c0 = mb0 + m, c1 = mb1 + m, c2 = mb2 + m;
          if (relsh[c0] == r) hS[c0*TS + f] = f2bf(acc0[reg]);
          if (relsh[c1] == r) hS[c1*TS + f] = f2bf(acc1[reg]);
          if (c2 < 64 && relsh[c2] == r) hS[c2*TS + f] = f2bf(acc2[reg]);
        }
      }
    }
    __syncthreads();
    for (int f = tid; f < NE; f += 256) {
      #pragma unroll
      for (int p = 5; p <= 15; p++) {
        int nc = (p == 15) ? 3 : 4;
        float sum = 0.f;
        for (int j = 0; j < nc; j++) sum += bf2f(hS[(4*p+1+j)*TS + f]);
        float v = bf2f(hS[p*TS + f]) * sum * (1.0f/(float)nc);
        hS[p*TS + f] = f2bf(v > 0.f ? v : 0.f);
      }
    }
    __syncthreads();
  }
  // Phase L2
  {
    bf16x8 af[10];
    #pragma unroll
    for (int ks = 0; ks < 10; ks++)
      af[ks] = *reinterpret_cast<const bf16x8*>(&hS[(5+mrow)*TS + ks*32 + quad*8]);
    __syncthreads();
    for (int pr = wave; pr < 57; pr += 4) {
      int r = pr / 19, nt = pr % 19;
      const ushort* Wb = &Wbf[(size_t)((r*20 + nt)*10)*64*8];
      f32x4 acc = f32x4{0.f,0.f,0.f,0.f};
      #pragma unroll
      for (int ks = 0; ks < 10; ks++) {
        bf16x8 bf = *reinterpret_cast<const bf16x8*>(&Wb[((size_t)ks*64 + lane)*8]);
        acc = __builtin_amdgcn_mfma_f32_16x16x32_bf16(af[ks], bf, acc, 0, 0, 0);
      }
      int f = nt*16 + mrow;
      if (f < NE) {
        #pragma unroll
        for (int reg = 0; reg < 4; reg++) {
          int c = 5 + quad*4 + reg;
          if (relsh[c] == r) hS[c*TS + f] = f2bf(acc[reg]);
        }
      }
    }
    __syncthreads();
    for (int f = tid; f < NE; f += 256) {
      #pragma unroll
      for (int p = 1; p <= 4; p++) {
        float sum = 0.f;
        #pragma unroll
        for (int j = 0; j < 4; j++) sum += bf2f(hS[(4*p+1+j)*TS + f]);
        float v = bf2f(hS[p*TS + f]) * sum * 0.25f;
        hS[p*TS + f] = f2bf(v > 0.f ? v : 0.f);
      }
    }
    __syncthreads();
  }
  // Phase L1
  {
    bool rp0 = (relsh[1]==0)|(relsh[2]==0)|(relsh[3]==0)|(relsh[4]==0);
    bool rp1 = (relsh[1]==1)|(relsh[2]==1)|(relsh[3]==1)|(relsh[4]==1);
    bool rp2 = (relsh[1]==2)|(relsh[2]==2)|(relsh[3]==2)|(relsh[4]==2);
    bf16x8 af[10];
    #pragma unroll
    for (int ks = 0; ks < 10; ks++)
      af[ks] = *reinterpret_cast<const bf16x8*>(&hS[(1+min(mrow,3))*TS + ks*32 + quad*8]);
    __syncthreads();
    for (int pr = wave; pr < 57; pr += 4) {
      int r = pr / 19, nt = pr % 19;
      if ((r==0 && !rp0) || (r==1 && !rp1) || (r==2 && !rp2)) continue;
      const ushort* Wb = &Wbf[(size_t)((r*20 + nt)*10)*64*8];
      f32x4 acc = f32x4{0.f,0.f,0.f,0.f};
      #pragma unroll
      for (int ks = 0; ks < 10; ks++) {
        bf16x8 bf = *reinterpret_cast<const bf16x8*>(&Wb[((size_t)ks*64 + lane)*8]);
        acc = __builtin_amdgcn_mfma_f32_16x16x32_bf16(af[ks], bf, acc, 0, 0, 0);
      }
      int f = nt*16 + mrow;
      if (f < NE) {
        #pragma unroll
        for (int reg = 0; reg < 4; reg++) {
          int m = quad*4 + reg;
          if (m < 4 && relsh[1+m] == r) hS[(1+m)*TS + f] = f2bf(acc[reg]);
        }
      }
    }
    __syncthreads();
    for (int f = tid; f < NE; f += 256) {
      float sum = 0.f;
      #pragma unroll
      for (int c = 1; c <= 4; c++) sum += bf2f(hS[c*TS + f]);
      float v = bf2f(hS[0*TS + f]) * sum * 0.25f;
      root[(size_t)sb*NE + f] = v > 0.f ? v : 0.f;
    }
  }
}

// ---------------- k_feat: X (concat feature) in A-frag swizzled bf16 (R2) ----
constexpr int FEAT_ITEMS  = KT0*16*64;          // 58,368
constexpr int FEAT_BLOCKS = FEAT_ITEMS/256;     // 228 exactly

__global__ __launch_bounds__(256)
void k_feat(const float* __restrict__ rep, const float* __restrict__ root,
            ushort* __restrict__ Xsw) {
  int t = blockIdx.x*256 + threadIdx.x;
  int lane = t & 63, g = t >> 6;
  int mt = g % 16, kt = g / 16;
  int b  = mt*16 + (lane & 15);
  int kb = kt*32 + (lane >> 4)*8;
  const float* rp = rep  + (size_t)b*NE;
  const float* rh = rep  + (size_t)(NB+b)*NE;
  const float* tp = root + (size_t)b*NE;
  const float* th = root + (size_t)(NB+b)*NE;
  ushort v[8];
  #pragma unroll
  for (int i = 0; i < 8; i++) {
    int k = kb + i;
    float x = 0.f;
    if (k < 6*NE) {
      int seg = k / NE, e = k - seg*NE;
      switch (seg) {
        case 0:  x = rp[e]; break;
        case 1:  x = rh[e]; break;
        case 2:  x = rp[e] - rh[e]; break;
        case 3:  x = rp[e] * rh[e]; break;
        case 4:  x = tp[e] - th[e]; break;
        default: x = tp[e] * th[e]; break;
      }
    }
    v[i] = f2bf(x);
  }
  *reinterpret_cast<int4*>(&Xsw[(size_t)t*8]) = *reinterpret_cast<const int4*>(v);
}

// ---------------- k_fc: one FC layer, grid (16 m-tiles, 10 j-groups) --------
// Block: 16 rows x 64 cols output; 4 waves split K 4-way, LDS reduce.
// mode 0: A = Xsw (A-frag swizzled). mode 1: A = h bf16 row-major [NB][HP].
__global__ __launch_bounds__(256)
void k_fc(const ushort* __restrict__ A, const ushort* __restrict__ Wsw,
          const float* __restrict__ bias, ushort* __restrict__ hout,
          int nkt, int mode) {
  __shared__ __align__(16) float red[4*4*64*4];   // 16 KB: [q][wv][lane][4]
  const int tid = threadIdx.x, wv = tid >> 6, lane = tid & 63;
  const int bx = blockIdx.x, by = blockIdx.y;

  f32x4 acc[4];
  #pragma unroll
  for (int q = 0; q < 4; q++) acc[q] = f32x4{0.f,0.f,0.f,0.f};

  for (int kt = wv; kt < nkt; kt += 4) {
    bf16x8 a;
    if (mode == 0)
      a = *reinterpret_cast<const bf16x8*>(&A[(((size_t)kt*16 + bx)*64 + lane)*8]);
    else
      a = *reinterpret_cast<const bf16x8*>(
          &A[(size_t)(bx*16 + (lane & 15))*HP + kt*32 + (lane >> 4)*8]);
    #pragma unroll
    for (int q = 0; q < 4; q++) {
      bf16x8 w = *reinterpret_cast<const bf16x8*>(
          &Wsw[(((size_t)kt*NJT + by*4 + q)*64 + lane)*8]);
      acc[q] = __builtin_amdgcn_mfma_f32_16x16x32_bf16(a, w, acc[q], 0, 0, 0);
    }
  }
  #pragma unroll
  for (int q = 0; q < 4; q++)
    *reinterpret_cast<f32x4*>(&red[(((size_t)q*4 + wv)*64 + lane)*4]) = acc[q];
  __syncthreads();
  // wave wv finalizes acc index q = wv
  f32x4 s{0.f,0.f,0.f,0.f};
  #pragma unroll
  for (int w = 0; w < 4; w++) {
    f32x4 p = *reinterpret_cast<f32x4*>(&red[(((size_t)wv*4 + w)*64 + lane)*4]);
    s[0] += p[0]; s[1] += p[1]; s[2] += p[2]; s[3] += p[3];
  }
  int row0 = bx*16 + (lane >> 4)*4;
  int j = (by*4 + wv)*16 + (lane & 15);
  if (j < 608) {
    float bj = (j < NH) ? bias[j] : 0.f;
    #pragma unroll
    for (int r = 0; r < 4; r++) {
      float v = s[r] + bj;
      v = v > 0.f ? v : 0.f;
      hout[(size_t)(row0 + r)*HP + j] = (j < NH) ? f2bf(v) : (ushort)0;
    }
  }
}

// ---------------- k_out: 600->3, h3 bf16 (relu already applied) (R2) --------
__global__ __launch_bounds__(64)
void k_out(const ushort* __restrict__ h3, const float* __restrict__ Wout,
           const float* __restrict__ bout, float* __restrict__ out) {
  int b = blockIdx.x, tid = threadIdx.x;
  float a0 = 0.f, a1 = 0.f, a2 = 0.f;
  for (int k = tid; k < NH; k += 64) {
    float xv = bf2f(h3[(size_t)b*HP + k]);
    a0 += xv * Wout[k];
    a1 += xv * Wout[NH + k];
    a2 += xv * Wout[2*NH + k];
  }
  #pragma unroll
  for (int off = 32; off > 0; off >>= 1) {
    a0 += __shfl_down(a0, off, 64);
    a1 += __shfl_down(a1, off, 64);
    a2 += __shfl_down(a2, off, 64);
  }
  if (tid == 0) {
    out[b*3 + 0] = a0 + bout[0];
    out[b*3 + 1] = a1 + bout[1];
    out[b*3 + 2] = a2 + bout[2];
  }
}

// ---------------- launch ----------------
extern "C" void kernel_launch(void* const* d_in, const int* in_sizes, int n_in,
                              void* d_out, int out_size, void* d_ws, size_t ws_size,
                              hipStream_t stream) {
  const int*   px    = (const int*)d_in[0];
  const int*   hx    = (const int*)d_in[1];
  const int*   pwi   = (const int*)d_in[2];
  const int*   prel  = (const int*)d_in[3];
  const int*   hwi   = (const int*)d_in[4];
  const int*   hrel  = (const int*)d_in[5];
  // d_in[6]=parent, d_in[7]=level: fixed 4-ary tree, hardcoded
  const float* Etab  = (const float*)d_in[8];
  const float* Wenc  = (const float*)d_in[9];
  const float* W0w   = (const float*)d_in[10];
  const float* W0b   = (const float*)d_in[11];
  const float* W1w   = (const float*)d_in[12];
  const float* W1b   = (const float*)d_in[13];
  const float* W2w   = (const float*)d_in[14];
  const float* W2b   = (const float*)d_in[15];
  const float* Woutw = (const float*)d_in[16];
  const float* Woutb = (const float*)d_in[17];

  float* ws   = (float*)d_ws;
  float*  rep  = ws + OFF_REP;
  float*  root = ws + OFF_ROOT;
  ushort* Wbf  = (ushort*)(ws + OFF_WBF);
  ushort* W0S  = (ushort*)(ws + OFF_W0S);
  ushort* W1S  = (ushort*)(ws + OFF_W1S);
  ushort* W2S  = (ushort*)(ws + OFF_W2S);
  ushort* Xsw  = (ushort*)(ws + OFF_XSW);
  ushort* h1   = (ushort*)(ws + OFF_H1);
  ushort* h2   = (ushort*)(ws + OFF_H2);
  ushort* h3   = (ushort*)(ws + OFF_H3);
  float* outp = (float*)d_out;

  k_setup<<<dim3(SETUP_BLOCKS), dim3(256), 0, stream>>>(
      Wenc, W0w, W1w, W2w, Wbf, W0S, W1S, W2S);
  k_tree<<<dim3(2*NB), dim3(256), 0, stream>>>(
      px, hx, pwi, prel, hwi, hrel, Etab, Wbf, rep, root);
  k_feat<<<dim3(FEAT_BLOCKS), dim3(256), 0, stream>>>(rep, root, Xsw);
  k_fc<<<dim3(16,10), dim3(256), 0, stream>>>(Xsw, W0S, W0b, h1, KT0, 0);
  k_fc<<<dim3(16,10), dim3(256), 0, stream>>>(h1,  W1S, W1b, h2, KT1, 1);
  k_fc<<<dim3(16,10), dim3(256), 0, stream>>>(h2,  W2S, W2b, h3, KT1, 1);
  k_out<<<dim3(NB), dim3(64), 0, stream>>>(h3, Woutw, Woutb, outp);
}